// Round 17
// baseline (175.876 us; speedup 1.0000x reference)
//
#include <hip/hip_runtime.h>
#include <math.h>

#define B_ 2
#define T_ 2048
#define C_ 1024
#define H_ 16
#define D_ 64
#define NX_ 4194304
#define NWQ_ 3145728
#define NWP_ 1048576

typedef unsigned short u16;
typedef unsigned int u32;
typedef __bf16 bf16x8 __attribute__((ext_vector_type(8)));
typedef _Float16 f16x8 __attribute__((ext_vector_type(8)));
typedef __fp16 fp16x2 __attribute__((ext_vector_type(2)));
typedef float f32x4 __attribute__((ext_vector_type(4)));
typedef u16 u16x4 __attribute__((ext_vector_type(4)));

__device__ __forceinline__ u16 f2bf(float f) {
    union { float f; u32 u; } v; v.f = f;
    u32 r = v.u + 0x7fffu + ((v.u >> 16) & 1u);   // RNE
    return (u16)(r >> 16);
}

#define GLD_LDS(g, l) \
    __builtin_amdgcn_global_load_lds( \
        (const __attribute__((address_space(1))) u32*)(const void*)(g), \
        (__attribute__((address_space(3))) u32*)(void*)(l), 16, 0, 0)

// ---------------------------------------------------------------------------
// fused cast of the three fp32 inputs -> bf16, plus RoPE cos/sin table
// ---------------------------------------------------------------------------
__global__ __launch_bounds__(256) void cast_all(const float* __restrict__ x,
                                                const float* __restrict__ wq,
                                                const float* __restrict__ wp,
                                                u16* __restrict__ out,
                                                float* __restrict__ tab) {
    const int bid = blockIdx.x;
    if (bid >= 8192) {   // RoPE table: 65536 pairs, 2 pairs/thread
        const int k = (bid - 8192) * 256 + threadIdx.x;
        #pragma unroll
        for (int e = 0; e < 2; ++e) {
            const int pidx = 2 * k + e;
            const int t = pidx >> 5, i = pidx & 31;
            const float theta = __expf(-0.2878231366f * (float)i);
            float sn, cs;
            __sincosf((float)t * theta, &sn, &cs);
            *(float2*)(tab + pidx * 2) = make_float2(cs, sn);
        }
        return;
    }
    const int i = (bid * 256 + threadIdx.x) * 4;
    const float* src;
    int off;
    if (i < NX_) { src = x; off = i; }
    else if (i < NX_ + NWQ_) { src = wq; off = i - NX_; }
    else { src = wp; off = i - NX_ - NWQ_; }
    float4 v = *(const float4*)(src + off);
    u16x4 o;
    o.x = f2bf(v.x); o.y = f2bf(v.y); o.z = f2bf(v.z); o.w = f2bf(v.w);
    *(u16x4*)(out + i) = o;
}

// ---------------------------------------------------------------------------
// bf16 GEMM, 128xBN tile, BK=64, XOR-swizzled LDS. Out = A[M][K] @ Bm[N][K]^T.
// EPI 0: fp32 output. EPI 1: fused RoPE + q/k/v split.
// DBUF 1: counted-vmcnt double-buffer (depth-1 prefetch — R13-verified, but
//   ~160cy compute phase cannot cover ~200-300cy L2 latency -> 23% MfmaUtil).
// DBUF 2: stage-early + __syncthreads (spill-robust).
// DBUF 3: counted-vmcnt TRIPLE-buffer, prefetch depth 3 — each tile gets
//   ~2 compute phases + 4 barriers (~800cy) of cover before use. LDS 72 KB.
//   vmcnt counting exact at BN=64 (68 VGPR, no spills — R14's failure mode
//   was spill traffic at BN=128's pressure). In-order VMEM completion:
//   <=12 outstanding <=> oldest tile's 6 loads landed.
// ---------------------------------------------------------------------------
template <int EPI, int DBUF, int BN>
__global__ __launch_bounds__(256) void gemm64(const u16* __restrict__ A,
                                              const u16* __restrict__ Bm,
                                              float* __restrict__ OutF,
                                              u16* __restrict__ qb,
                                              u16* __restrict__ kb,
                                              u16* __restrict__ vt,
                                              const float* __restrict__ tab,
                                              int M, int N, int K) {
    constexpr int NBUF = (DBUF == 3) ? 3 : (DBUF ? 2 : 1);
    constexpr int MI = (BN == 128) ? 4 : 2;   // m-frags per wave
    constexpr int BCH = BN / 32;              // B staging chunks per wave
    __shared__ u16 As[NBUF][128 * 64];
    __shared__ u16 Bs[NBUF][BN * 64];
    const int tid = threadIdx.x;
    const int lane = tid & 63;
    const int wave = tid >> 6;
    const int wm = (BN == 128) ? (wave >> 1) * 64 : wave * 32;
    const int wn = (BN == 128) ? (wave & 1) * 64 : 0;
    const int m0 = blockIdx.y * 128;
    const int n0 = blockIdx.x * BN;

    const int rl = lane >> 3;
    const int sg = ((lane & 7) ^ rl) * 8;
    const u16* gA[4]; const u16* gB[BCH];
    int lofA[4], lofB[BCH];
    #pragma unroll
    for (int c = 0; c < 4; ++c) {
        const int ca = wave * 4 + c;
        gA[c] = A + (size_t)(m0 + ca * 8 + rl) * K + sg;
        lofA[c] = ca * 512;
    }
    #pragma unroll
    for (int c = 0; c < BCH; ++c) {
        const int cb = wave * BCH + c;
        gB[c] = Bm + (size_t)(n0 + cb * 8 + rl) * K + sg;
        lofB[c] = cb * 512;
    }

    const int col = lane & 15;
    const int quad = lane >> 4;
    int aoff[2][MI], boff[2][4];
    #pragma unroll
    for (int ks = 0; ks < 2; ++ks) {
        #pragma unroll
        for (int i = 0; i < MI; ++i) {
            const int m = wm + i * 16 + col;
            aoff[ks][i] = (m >> 3) * 512 + (m & 7) * 64 +
                          ((((ks << 2) | quad)) ^ (m & 7)) * 8;
        }
        #pragma unroll
        for (int j = 0; j < 4; ++j) {
            const int n = wn + j * 16 + col;
            boff[ks][j] = (n >> 3) * 512 + (n & 7) * 64 +
                          ((((ks << 2) | quad)) ^ (n & 7)) * 8;
        }
    }

    f32x4 acc[MI][4] = {};

#define GEMM_STAGE(BUFI, KOFF)                                                 \
    {                                                                          \
        _Pragma("unroll")                                                      \
        for (int c = 0; c < 4; ++c)                                            \
            GLD_LDS(gA[c] + (KOFF), &As[BUFI][lofA[c]]);                       \
        _Pragma("unroll")                                                      \
        for (int c = 0; c < BCH; ++c)                                          \
            GLD_LDS(gB[c] + (KOFF), &Bs[BUFI][lofB[c]]);                       \
    }

#define GEMM_COMPUTE(ASB, BSB)                                                 \
    {                                                                          \
        _Pragma("unroll")                                                      \
        for (int ks = 0; ks < 2; ++ks) {                                       \
            bf16x8 a[MI], b[4];                                                \
            _Pragma("unroll")                                                  \
            for (int i = 0; i < MI; ++i)                                       \
                a[i] = *(const bf16x8*)((ASB) + aoff[ks][i]);                  \
            _Pragma("unroll")                                                  \
            for (int j = 0; j < 4; ++j)                                        \
                b[j] = *(const bf16x8*)((BSB) + boff[ks][j]);                  \
            _Pragma("unroll")                                                  \
            for (int i = 0; i < MI; ++i)                                       \
                _Pragma("unroll")                                              \
                for (int j = 0; j < 4; ++j)                                    \
                    acc[i][j] = __builtin_amdgcn_mfma_f32_16x16x32_bf16(       \
                        a[i], b[j], acc[i][j], 0, 0, 0);                       \
        }                                                                      \
    }

    if (DBUF == 1) {
        // counted-vmcnt double-buffer (R11/R13-verified)
        GEMM_STAGE(0, 0)
        __syncthreads();
        int buf = 0;
        for (int k0 = 64; k0 < K; k0 += 64) {
            asm volatile("s_barrier" ::: "memory");
            GEMM_STAGE(buf ^ 1, k0)
            if (BN == 64) asm volatile("s_waitcnt vmcnt(6)" ::: "memory");
            else          asm volatile("s_waitcnt vmcnt(8)" ::: "memory");
            asm volatile("s_barrier" ::: "memory");
            GEMM_COMPUTE(&As[buf][0], &Bs[buf][0])
            buf ^= 1;
        }
        asm volatile("s_waitcnt vmcnt(0)" ::: "memory");
        asm volatile("s_barrier" ::: "memory");
        GEMM_COMPUTE(&As[buf][0], &Bs[buf][0])
    } else if (DBUF == 2) {
        // stage-early + __syncthreads double-buffer (spill-robust)
        GEMM_STAGE(0, 0)
        __syncthreads();
        int buf = 0;
        for (int k0 = 64; k0 < K; k0 += 64) {
            GEMM_STAGE(buf ^ 1, k0)
            GEMM_COMPUTE(&As[buf][0], &Bs[buf][0])
            __syncthreads();
            buf ^= 1;
        }
        GEMM_COMPUTE(&As[buf][0], &Bs[buf][0])
    } else if (DBUF == 3) {
        // triple-buffer, depth-3 counted-vmcnt (BN=64 only: 6 loads/stage)
        const int NT = K / 64;     // >= 3
        GEMM_STAGE(0, 0)
        GEMM_STAGE(1, 64)
        GEMM_STAGE(2, 128)
        int buf = 0;
        for (int t = 0; t < NT; ++t) {
            // in-order completion: <=12 outstanding <=> tile t's 6 landed
            if (t + 3 <= NT)      asm volatile("s_waitcnt vmcnt(12)" ::: "memory");
            else if (t + 2 == NT) asm volatile("s_waitcnt vmcnt(6)"  ::: "memory");
            else                  asm volatile("s_waitcnt vmcnt(0)"  ::: "memory");
            asm volatile("s_barrier" ::: "memory");   // tile t ready block-wide
            GEMM_COMPUTE(&As[buf][0], &Bs[buf][0])
            if (t + 3 < NT) {
                asm volatile("s_barrier" ::: "memory");  // reads of buf done
                GEMM_STAGE(buf, (t + 3) * 64)
            }
            buf = (buf == 2) ? 0 : buf + 1;
        }
    } else {
        for (int k0 = 0; k0 < K; k0 += 64) {
            __syncthreads();
            GEMM_STAGE(0, k0)
            __syncthreads();
            GEMM_COMPUTE(&As[0][0], &Bs[0][0])
        }
    }
#undef GEMM_COMPUTE
#undef GEMM_STAGE

    const int rq = quad * 4;
    if (EPI == 0) {
        #pragma unroll
        for (int i = 0; i < MI; ++i)
            #pragma unroll
            for (int j = 0; j < 4; ++j)
                #pragma unroll
                for (int r = 0; r < 4; ++r)
                    OutF[(size_t)(m0 + wm + i * 16 + rq + r) * N +
                         n0 + wn + j * 16 + col] = acc[i][j][r];
    } else {
        const int sslot = m0 >> 10;   // 0=q 1=k 2=v, block-uniform
        #pragma unroll
        for (int i = 0; i < MI; ++i) {
            const int gm = m0 + wm + i * 16 + rq;
            const int hh = (gm >> 6) & 15;
            const int dbase = gm & 63;
            #pragma unroll
            for (int j = 0; j < 4; ++j) {
                const int gt = n0 + wn + j * 16 + col;
                const int bb = gt >> 11;
                const int t = gt & (T_ - 1);
                const int bh = bb * H_ + hh;
                if (sslot < 2) {
                    const float4 cs4 = *(const float4*)(tab + t * 64 + dbase);
                    u16x4 ov;
                    ov[0] = f2bf(acc[i][j][0] * cs4.x - acc[i][j][1] * cs4.y);
                    ov[1] = f2bf(acc[i][j][1] * cs4.x + acc[i][j][0] * cs4.y);
                    ov[2] = f2bf(acc[i][j][2] * cs4.z - acc[i][j][3] * cs4.w);
                    ov[3] = f2bf(acc[i][j][3] * cs4.z + acc[i][j][2] * cs4.w);
                    u16* dst = (sslot == 0 ? qb : kb) +
                               ((size_t)bh * T_ + t) * D_ + dbase;
                    *(u16x4*)dst = ov;
                } else {
                    #pragma unroll
                    for (int r = 0; r < 4; ++r) {
                        union { _Float16 h; u16 u; } cv;
                        cv.h = (_Float16)acc[i][j][r];
                        vt[((size_t)bh * D_ + dbase + r) * T_ + t] = cv.u;
                    }
                }
            }
        }
    }
}

// ---------------------------------------------------------------------------
// Flash attention v14 (R12/R13, verified): 8-wave key-split, 512 blocks x
// 512 threads, uniform pairing, counted-vmcnt(4), linear partial combine.
// ---------------------------------------------------------------------------
__global__ __launch_bounds__(512, 4) void attn_mfma(const u16* __restrict__ qb,
                                                    const u16* __restrict__ kb,
                                                    const u16* __restrict__ vtg,
                                                    u16* __restrict__ y) {
    __shared__ u16 Ks[2][2 * 4096];  // [buf][sub 2][key 64][d 64] swizzled
    __shared__ u16 Vt[2][2 * 4096];  // [buf][sub 2][d 64][key 64] swizzled
    const int id = blockIdx.x;      // 0..511
    const int bh = id & 31;
    const int pr = id >> 5;         // 0..15
    const int b = bh >> 4, h = bh & 15;
    const int tid = threadIdx.x;
    const int lane = tid & 63;
    const int wave = tid >> 6;      // 0..7
    const int grp = wave >> 2;      // key-parity group: 0=even subs, 1=odd
    const int wq = wave & 3;        // q-row group (16 rows each)
    const int col = lane & 15;
    const int quad = lane >> 4;

    // staging: wave w stages rows 8w..8w+7 of both 64-key subs (4 GLD/wave)
    const int rl = lane >> 3;
    const int sg = ((lane & 7) ^ rl) * 8;
    const u16* kg = kb + ((size_t)bh * T_ + wave * 8 + rl) * D_ + sg;
    const u16* vg = vtg + ((size_t)bh * D_ + wave * 8 + rl) * T_ + sg;
    const int lco = wave * 512;

    int koff[2][4];   // swizzled frag offsets (K: row=key; V: row=d)
    #pragma unroll
    for (int ks = 0; ks < 2; ++ks)
        #pragma unroll
        for (int n = 0; n < 4; ++n) {
            const int rr = n * 16 + col;
            koff[ks][n] = (rr >> 3) * 512 + (rr & 7) * 64 +
                          ((((ks << 2) | quad)) ^ (rr & 7)) * 8;
        }

    // shuffle sources for P C/D -> A-operand transform
    const int srcA = col + ((quad & 1) << 5);   // lane of q-group q' = 2*(quad&1)
    const int srcB = srcA + 16;                 // q' + 1
    const bool hi = (quad >> 1) != 0;           // use n = 2ks+1 ?

#define STAGE2(BUF, C0)                                                        \
    {                                                                          \
        const size_t jj = (size_t)(C0) * 64;                                   \
        GLD_LDS(kg + jj * D_, &Ks[BUF][lco]);                                  \
        GLD_LDS(vg + jj, &Vt[BUF][lco]);                                       \
        GLD_LDS(kg + (jj + 64) * D_, &Ks[BUF][4096 + lco]);                    \
        GLD_LDS(vg + jj + 64, &Vt[BUF][4096 + lco]);                           \
    }

#define CHUNK_COMPUTE(BUF, SUB, J0, DIAG)                                      \
    {                                                                          \
        const int j0_ = (J0);                                                  \
        const u16* ksb = &Ks[BUF][(SUB) * 4096];                               \
        const u16* vsb = &Vt[BUF][(SUB) * 4096];                               \
        /* S^T = K Q^T : A = K (m=key), B = Q (n=q) */                         \
        f32x4 s[4] = {};                                                       \
        __builtin_amdgcn_s_setprio(1);                                         \
        _Pragma("unroll")                                                      \
        for (int ks = 0; ks < 2; ++ks)                                         \
            _Pragma("unroll")                                                  \
            for (int n = 0; n < 4; ++n) {                                      \
                const bf16x8 kf = *(const bf16x8*)(ksb + koff[ks][n]);         \
                s[n] = __builtin_amdgcn_mfma_f32_16x16x32_bf16(                \
                    kf, qf[ks], s[n], 0, 0, 0);                                \
            }                                                                  \
        __builtin_amdgcn_s_setprio(0);                                         \
        /* P = exp2(S*scale*log2e), masked on diagonal chunk; pack f16 */      \
        u32 pk[4][2];                                                          \
        _Pragma("unroll")                                                      \
        for (int n = 0; n < 4; ++n) {                                          \
            float p[4];                                                        \
            _Pragma("unroll")                                                  \
            for (int r = 0; r < 4; ++r) {                                      \
                float pv = __builtin_amdgcn_exp2f(s[n][r] * 0.1803368801f);    \
                if (DIAG && (j0_ + n * 16 + quad * 4 + r > qrow)) pv = 0.0f;   \
                p[r] = pv;                                                     \
                lsv[r] += pv;                                                  \
            }                                                                  \
            union { fp16x2 h; u32 u; } c0u, c1u;                               \
            c0u.h = __builtin_amdgcn_cvt_pkrtz(p[0], p[1]);                    \
            c1u.h = __builtin_amdgcn_cvt_pkrtz(p[2], p[3]);                    \
            pk[n][0] = c0u.u;                                                  \
            pk[n][1] = c1u.u;                                                  \
        }                                                                      \
        /* O += P V : A-frag of P built by in-wave shuffles */                 \
        _Pragma("unroll")                                                      \
        for (int ks = 0; ks < 2; ++ks) {                                       \
            const int nl = 2 * ks, nh = nl + 1;                                \
            const u32 w0a = __shfl(pk[nl][0], srcA);                           \
            const u32 w0b = __shfl(pk[nh][0], srcA);                           \
            const u32 w1a = __shfl(pk[nl][1], srcA);                           \
            const u32 w1b = __shfl(pk[nh][1], srcA);                           \
            const u32 w2a = __shfl(pk[nl][0], srcB);                           \
            const u32 w2b = __shfl(pk[nh][0], srcB);                           \
            const u32 w3a = __shfl(pk[nl][1], srcB);                           \
            const u32 w3b = __shfl(pk[nh][1], srcB);                           \
            union { u32 u[4]; f16x8 v; } af;                                   \
            af.u[0] = hi ? w0b : w0a;                                          \
            af.u[1] = hi ? w1b : w1a;                                          \
            af.u[2] = hi ? w2b : w2a;                                          \
            af.u[3] = hi ? w3b : w3a;                                          \
            __builtin_amdgcn_s_setprio(1);                                     \
            _Pragma("unroll")                                                  \
            for (int n = 0; n < 4; ++n) {                                      \
                const f16x8 vf = *(const f16x8*)(vsb + koff[ks][n]);           \
                o[n] = __builtin_amdgcn_mfma_f32_16x16x32_f16(                 \
                    af.v, vf, o[n], 0, 0, 0);                                  \
            }                                                                  \
            __builtin_amdgcn_s_setprio(0);                                     \
        }                                                                      \
    }

    for (int half = 0; half < 2; ++half) {
        const int qt = half ? pr : (31 - pr);
        const int q0 = qt * 64;
        const int qrow = q0 + wq * 16 + col;
        const int nchunks = qt + 1;
        const int niter = (nchunks + 1) >> 1;

        // Q B-fragments: lane holds Q[q=col][d=ks*32+quad*8+j]
        const u16* qbase = qb + ((size_t)bh * T_ + q0 + wq * 16) * D_;
        bf16x8 qf[2];
        #pragma unroll
        for (int ks = 0; ks < 2; ++ks)
            qf[ks] = *(const bf16x8*)(qbase + col * D_ + ks * 32 + quad * 8);

        f32x4 o[4] = {};
        float lsv[4] = {};

        // guard LDS reuse across halves / combine scratch (full drain)
        __syncthreads();
        // prologue: sub-tiles {0,1} into buf 0 (4 loads in flight)
        STAGE2(0, 0)

        int buf = 0;
        for (int it = 0; it + 1 < niter; ++it) {
            // read-safety: all waves done reading the buffer we overwrite
            asm volatile("s_barrier" ::: "memory");
            STAGE2(buf ^ 1, 2 * (it + 1))   // +4 loads (8 outstanding)
            // wait for the OLDER 4 (buf's data); prefetch stays in flight
            asm volatile("s_waitcnt vmcnt(4)" ::: "memory");
            asm volatile("s_barrier" ::: "memory");
            // group's sub-chunk c = 2*it+grp <= nchunks-2 < qt: never diag
            CHUNK_COMPUTE(buf, grp, (2 * it + grp) * 64, false)
            buf ^= 1;
        }
        __syncthreads();   // full drain for the final iter's DMA
        {
            const int cf = 2 * (niter - 1) + grp;
            if (cf <= qt) {
                if (cf == qt) { CHUNK_COMPUTE(buf, grp, cf * 64, true) }
                else         { CHUNK_COMPUTE(buf, grp, cf * 64, false) }
            }
        }

        // combine group partials (linear: no-max softmax) via LDS scratch,
        // then group 0 reduces + writes. Scratch overlays Ks (dead now).
        __syncthreads();   // all K/V reads done before scratch overwrite
        float* scratch = (float*)&Ks[0][0];   // 4 waves*64 lanes*21 f32
        const int sidx = (wq * 64 + lane) * 21;
        if (grp == 1) {
            #pragma unroll
            for (int n = 0; n < 4; ++n)
                #pragma unroll
                for (int r = 0; r < 4; ++r)
                    scratch[sidx + n * 4 + r] = o[n][r];
            #pragma unroll
            for (int r = 0; r < 4; ++r)
                scratch[sidx + 16 + r] = lsv[r];
        }
        __syncthreads();
        if (grp == 0) {
            #pragma unroll
            for (int n = 0; n < 4; ++n)
                #pragma unroll
                for (int r = 0; r < 4; ++r)
                    o[n][r] += scratch[sidx + n * 4 + r];
            #pragma unroll
            for (int r = 0; r < 4; ++r)
                lsv[r] += scratch[sidx + 16 + r];

            float l = (lsv[0] + lsv[1]) + (lsv[2] + lsv[3]);
            l += __shfl_xor(l, 16);
            l += __shfl_xor(l, 32);
            const float inv = 1.0f / l;
            float invr[4];
            #pragma unroll
            for (int r = 0; r < 4; ++r)
                invr[r] = __shfl(inv, quad * 4 + r);   // inv for q = quad*4+r
            #pragma unroll
            for (int r = 0; r < 4; ++r) {
                const int row = q0 + wq * 16 + quad * 4 + r;
                u16* yp = y + (size_t)(b * T_ + row) * C_ + h * D_;
                #pragma unroll
                for (int n = 0; n < 4; ++n)
                    yp[n * 16 + col] = f2bf(o[n][r] * invr[r]);
            }
        }
    }
#undef CHUNK_COMPUTE
#undef STAGE2
}

// ---------------------------------------------------------------------------
// Launch
// ---------------------------------------------------------------------------
extern "C" void kernel_launch(void* const* d_in, const int* in_sizes, int n_in,
                              void* d_out, int out_size, void* d_ws, size_t ws_size,
                              hipStream_t stream) {
    const float* x      = (const float*)d_in[0];
    const float* w_qkv  = (const float*)d_in[1];
    const float* w_proj = (const float*)d_in[2];
    float* out = (float*)d_out;

    const int M = B_ * T_;                   // 4096
    u16* xb  = (u16*)d_ws;
    u16* wqb = xb + NX_;
    u16* wpb = wqb + NWQ_;
    u16* qb  = wpb + NWP_;
    u16* kb  = qb + NX_;
    u16* vt  = kb + NX_;     // f16 (b,h,d,t)
    u16* yb  = vt + NX_;     // bf16 (b,t,h,d)
    float* tab = (float*)(yb + NX_);   // RoPE table, 512 KB

    cast_all<<<8192 + 128, 256, 0, stream>>>(x, w_qkv, w_proj, xb, tab);

    // qkv^T = w_qkv @ x^T, fused RoPE + split into qb/kb (bf16), vt (f16)
    // BN=64 + depth-3 triple-buffer: 1536 blocks, LDS 72 KB -> 2 blocks/CU;
    // each tile gets ~800cy of issue-to-use cover (vs ~160cy at depth 1,
    // which couldn't hide the ~200-300cy L2 latency -> 23% MfmaUtil)
    gemm64<1, 3, 64><<<dim3(M / 64, 3 * C_ / 128), 256, 0, stream>>>(
        wqb, xb, nullptr, qb, kb, vt, tab, 3 * C_, M, C_);

    attn_mfma<<<512, 512, 0, stream>>>(qb, kb, vt, yb);

    // out = y @ w_proj^T -> fp32
    // BN=64 + depth-3 triple-buffer: 512 blocks = 2/CU either way (no
    // occupancy cost), LDS 72 KB
    gemm64<0, 3, 64><<<dim3(C_ / 64, M / 128), 256, 0, stream>>>(
        yb, wpb, out, nullptr, nullptr, nullptr, nullptr, M, C_, C_);
}

// Round 18
// 169.801 us; speedup vs baseline: 1.0358x; 1.0358x over previous
//
#include <hip/hip_runtime.h>
#include <math.h>

#define B_ 2
#define T_ 2048
#define C_ 1024
#define H_ 16
#define D_ 64
#define NX_ 4194304
#define NWQ_ 3145728
#define NWP_ 1048576

typedef unsigned short u16;
typedef unsigned int u32;
typedef __bf16 bf16x8 __attribute__((ext_vector_type(8)));
typedef _Float16 f16x8 __attribute__((ext_vector_type(8)));
typedef __fp16 fp16x2 __attribute__((ext_vector_type(2)));
typedef float f32x4 __attribute__((ext_vector_type(4)));
typedef u16 u16x4 __attribute__((ext_vector_type(4)));

__device__ __forceinline__ u16 f2bf(float f) {
    union { float f; u32 u; } v; v.f = f;
    u32 r = v.u + 0x7fffu + ((v.u >> 16) & 1u);   // RNE
    return (u16)(r >> 16);
}

#define GLD_LDS(g, l) \
    __builtin_amdgcn_global_load_lds( \
        (const __attribute__((address_space(1))) u32*)(const void*)(g), \
        (__attribute__((address_space(3))) u32*)(void*)(l), 16, 0, 0)

// ---------------------------------------------------------------------------
// fused cast of the three fp32 inputs -> bf16, plus RoPE cos/sin table
// ---------------------------------------------------------------------------
__global__ __launch_bounds__(256) void cast_all(const float* __restrict__ x,
                                                const float* __restrict__ wq,
                                                const float* __restrict__ wp,
                                                u16* __restrict__ out,
                                                float* __restrict__ tab) {
    const int bid = blockIdx.x;
    if (bid >= 8192) {   // RoPE table: 65536 pairs, 2 pairs/thread
        const int k = (bid - 8192) * 256 + threadIdx.x;
        #pragma unroll
        for (int e = 0; e < 2; ++e) {
            const int pidx = 2 * k + e;
            const int t = pidx >> 5, i = pidx & 31;
            const float theta = __expf(-0.2878231366f * (float)i);
            float sn, cs;
            __sincosf((float)t * theta, &sn, &cs);
            *(float2*)(tab + pidx * 2) = make_float2(cs, sn);
        }
        return;
    }
    const int i = (bid * 256 + threadIdx.x) * 4;
    const float* src;
    int off;
    if (i < NX_) { src = x; off = i; }
    else if (i < NX_ + NWQ_) { src = wq; off = i - NX_; }
    else { src = wp; off = i - NX_ - NWQ_; }
    float4 v = *(const float4*)(src + off);
    u16x4 o;
    o.x = f2bf(v.x); o.y = f2bf(v.y); o.z = f2bf(v.z); o.w = f2bf(v.w);
    *(u16x4*)(out + i) = o;
}

// ---------------------------------------------------------------------------
// bf16 GEMM, 128xBN tile, BK=64, XOR-swizzled LDS. Out = A[M][K] @ Bm[N][K]^T.
// EPI 0: fp32 output. EPI 1: fused RoPE + q/k/v split.
// FINAL CONFIG (R13, session best): both GEMMs <*, 1, 64> — BN=64,
// depth-1 counted-vmcnt double-buffer, 3 blocks/CU for gemm1.
// Exploration matrix (gemm1 µs): BN64/d1=43.9 < BN64/none~46 < BN64/d3=48.6
// < BN128/drain=51.2 < BN128/dbuf2=56.4. Occupancy (>=3 blocks/CU) dominates
// both LDS-per-MFMA efficiency and prefetch depth at this 16-step K-loop.
// ---------------------------------------------------------------------------
template <int EPI, int DBUF, int BN>
__global__ __launch_bounds__(256) void gemm64(const u16* __restrict__ A,
                                              const u16* __restrict__ Bm,
                                              float* __restrict__ OutF,
                                              u16* __restrict__ qb,
                                              u16* __restrict__ kb,
                                              u16* __restrict__ vt,
                                              const float* __restrict__ tab,
                                              int M, int N, int K) {
    constexpr int NBUF = (DBUF == 3) ? 3 : (DBUF ? 2 : 1);
    constexpr int MI = (BN == 128) ? 4 : 2;   // m-frags per wave
    constexpr int BCH = BN / 32;              // B staging chunks per wave
    __shared__ u16 As[NBUF][128 * 64];
    __shared__ u16 Bs[NBUF][BN * 64];
    const int tid = threadIdx.x;
    const int lane = tid & 63;
    const int wave = tid >> 6;
    const int wm = (BN == 128) ? (wave >> 1) * 64 : wave * 32;
    const int wn = (BN == 128) ? (wave & 1) * 64 : 0;
    const int m0 = blockIdx.y * 128;
    const int n0 = blockIdx.x * BN;

    const int rl = lane >> 3;
    const int sg = ((lane & 7) ^ rl) * 8;
    const u16* gA[4]; const u16* gB[BCH];
    int lofA[4], lofB[BCH];
    #pragma unroll
    for (int c = 0; c < 4; ++c) {
        const int ca = wave * 4 + c;
        gA[c] = A + (size_t)(m0 + ca * 8 + rl) * K + sg;
        lofA[c] = ca * 512;
    }
    #pragma unroll
    for (int c = 0; c < BCH; ++c) {
        const int cb = wave * BCH + c;
        gB[c] = Bm + (size_t)(n0 + cb * 8 + rl) * K + sg;
        lofB[c] = cb * 512;
    }

    const int col = lane & 15;
    const int quad = lane >> 4;
    int aoff[2][MI], boff[2][4];
    #pragma unroll
    for (int ks = 0; ks < 2; ++ks) {
        #pragma unroll
        for (int i = 0; i < MI; ++i) {
            const int m = wm + i * 16 + col;
            aoff[ks][i] = (m >> 3) * 512 + (m & 7) * 64 +
                          ((((ks << 2) | quad)) ^ (m & 7)) * 8;
        }
        #pragma unroll
        for (int j = 0; j < 4; ++j) {
            const int n = wn + j * 16 + col;
            boff[ks][j] = (n >> 3) * 512 + (n & 7) * 64 +
                          ((((ks << 2) | quad)) ^ (n & 7)) * 8;
        }
    }

    f32x4 acc[MI][4] = {};

#define GEMM_STAGE(BUFI, KOFF)                                                 \
    {                                                                          \
        _Pragma("unroll")                                                      \
        for (int c = 0; c < 4; ++c)                                            \
            GLD_LDS(gA[c] + (KOFF), &As[BUFI][lofA[c]]);                       \
        _Pragma("unroll")                                                      \
        for (int c = 0; c < BCH; ++c)                                          \
            GLD_LDS(gB[c] + (KOFF), &Bs[BUFI][lofB[c]]);                       \
    }

#define GEMM_COMPUTE(ASB, BSB)                                                 \
    {                                                                          \
        _Pragma("unroll")                                                      \
        for (int ks = 0; ks < 2; ++ks) {                                       \
            bf16x8 a[MI], b[4];                                                \
            _Pragma("unroll")                                                  \
            for (int i = 0; i < MI; ++i)                                       \
                a[i] = *(const bf16x8*)((ASB) + aoff[ks][i]);                  \
            _Pragma("unroll")                                                  \
            for (int j = 0; j < 4; ++j)                                        \
                b[j] = *(const bf16x8*)((BSB) + boff[ks][j]);                  \
            _Pragma("unroll")                                                  \
            for (int i = 0; i < MI; ++i)                                       \
                _Pragma("unroll")                                              \
                for (int j = 0; j < 4; ++j)                                    \
                    acc[i][j] = __builtin_amdgcn_mfma_f32_16x16x32_bf16(       \
                        a[i], b[j], acc[i][j], 0, 0, 0);                       \
        }                                                                      \
    }

    if (DBUF == 1) {
        // counted-vmcnt double-buffer (R11/R13-verified race-free;
        // BN=64: 68 VGPR, no spills -> hand vmcnt count is exact)
        GEMM_STAGE(0, 0)
        __syncthreads();
        int buf = 0;
        for (int k0 = 64; k0 < K; k0 += 64) {
            asm volatile("s_barrier" ::: "memory");
            GEMM_STAGE(buf ^ 1, k0)
            if (BN == 64) asm volatile("s_waitcnt vmcnt(6)" ::: "memory");
            else          asm volatile("s_waitcnt vmcnt(8)" ::: "memory");
            asm volatile("s_barrier" ::: "memory");
            GEMM_COMPUTE(&As[buf][0], &Bs[buf][0])
            buf ^= 1;
        }
        asm volatile("s_waitcnt vmcnt(0)" ::: "memory");
        asm volatile("s_barrier" ::: "memory");
        GEMM_COMPUTE(&As[buf][0], &Bs[buf][0])
    } else if (DBUF == 2) {
        // stage-early + __syncthreads double-buffer (spill-robust)
        GEMM_STAGE(0, 0)
        __syncthreads();
        int buf = 0;
        for (int k0 = 64; k0 < K; k0 += 64) {
            GEMM_STAGE(buf ^ 1, k0)
            GEMM_COMPUTE(&As[buf][0], &Bs[buf][0])
            __syncthreads();
            buf ^= 1;
        }
        GEMM_COMPUTE(&As[buf][0], &Bs[buf][0])
    } else if (DBUF == 3) {
        // triple-buffer, depth-3 counted-vmcnt (R17: slower — occupancy loss)
        const int NT = K / 64;
        GEMM_STAGE(0, 0)
        GEMM_STAGE(1, 64)
        GEMM_STAGE(2, 128)
        int buf = 0;
        for (int t = 0; t < NT; ++t) {
            if (t + 3 <= NT)      asm volatile("s_waitcnt vmcnt(12)" ::: "memory");
            else if (t + 2 == NT) asm volatile("s_waitcnt vmcnt(6)"  ::: "memory");
            else                  asm volatile("s_waitcnt vmcnt(0)"  ::: "memory");
            asm volatile("s_barrier" ::: "memory");
            GEMM_COMPUTE(&As[buf][0], &Bs[buf][0])
            if (t + 3 < NT) {
                asm volatile("s_barrier" ::: "memory");
                GEMM_STAGE(buf, (t + 3) * 64)
            }
            buf = (buf == 2) ? 0 : buf + 1;
        }
    } else {
        for (int k0 = 0; k0 < K; k0 += 64) {
            __syncthreads();
            GEMM_STAGE(0, k0)
            __syncthreads();
            GEMM_COMPUTE(&As[0][0], &Bs[0][0])
        }
    }
#undef GEMM_COMPUTE
#undef GEMM_STAGE

    const int rq = quad * 4;
    if (EPI == 0) {
        #pragma unroll
        for (int i = 0; i < MI; ++i)
            #pragma unroll
            for (int j = 0; j < 4; ++j)
                #pragma unroll
                for (int r = 0; r < 4; ++r)
                    OutF[(size_t)(m0 + wm + i * 16 + rq + r) * N +
                         n0 + wn + j * 16 + col] = acc[i][j][r];
    } else {
        const int sslot = m0 >> 10;   // 0=q 1=k 2=v, block-uniform
        #pragma unroll
        for (int i = 0; i < MI; ++i) {
            const int gm = m0 + wm + i * 16 + rq;
            const int hh = (gm >> 6) & 15;
            const int dbase = gm & 63;
            #pragma unroll
            for (int j = 0; j < 4; ++j) {
                const int gt = n0 + wn + j * 16 + col;
                const int bb = gt >> 11;
                const int t = gt & (T_ - 1);
                const int bh = bb * H_ + hh;
                if (sslot < 2) {
                    const float4 cs4 = *(const float4*)(tab + t * 64 + dbase);
                    u16x4 ov;
                    ov[0] = f2bf(acc[i][j][0] * cs4.x - acc[i][j][1] * cs4.y);
                    ov[1] = f2bf(acc[i][j][1] * cs4.x + acc[i][j][0] * cs4.y);
                    ov[2] = f2bf(acc[i][j][2] * cs4.z - acc[i][j][3] * cs4.w);
                    ov[3] = f2bf(acc[i][j][3] * cs4.z + acc[i][j][2] * cs4.w);
                    u16* dst = (sslot == 0 ? qb : kb) +
                               ((size_t)bh * T_ + t) * D_ + dbase;
                    *(u16x4*)dst = ov;
                } else {
                    #pragma unroll
                    for (int r = 0; r < 4; ++r) {
                        union { _Float16 h; u16 u; } cv;
                        cv.h = (_Float16)acc[i][j][r];
                        vt[((size_t)bh * D_ + dbase + r) * T_ + t] = cv.u;
                    }
                }
            }
        }
    }
}

// ---------------------------------------------------------------------------
// Flash attention v14 (R12/R13, verified): 8-wave key-split, 512 blocks x
// 512 threads, uniform pairing, counted-vmcnt(4), linear partial combine.
// ---------------------------------------------------------------------------
__global__ __launch_bounds__(512, 4) void attn_mfma(const u16* __restrict__ qb,
                                                    const u16* __restrict__ kb,
                                                    const u16* __restrict__ vtg,
                                                    u16* __restrict__ y) {
    __shared__ u16 Ks[2][2 * 4096];  // [buf][sub 2][key 64][d 64] swizzled
    __shared__ u16 Vt[2][2 * 4096];  // [buf][sub 2][d 64][key 64] swizzled
    const int id = blockIdx.x;      // 0..511
    const int bh = id & 31;
    const int pr = id >> 5;         // 0..15
    const int b = bh >> 4, h = bh & 15;
    const int tid = threadIdx.x;
    const int lane = tid & 63;
    const int wave = tid >> 6;      // 0..7
    const int grp = wave >> 2;      // key-parity group: 0=even subs, 1=odd
    const int wq = wave & 3;        // q-row group (16 rows each)
    const int col = lane & 15;
    const int quad = lane >> 4;

    // staging: wave w stages rows 8w..8w+7 of both 64-key subs (4 GLD/wave)
    const int rl = lane >> 3;
    const int sg = ((lane & 7) ^ rl) * 8;
    const u16* kg = kb + ((size_t)bh * T_ + wave * 8 + rl) * D_ + sg;
    const u16* vg = vtg + ((size_t)bh * D_ + wave * 8 + rl) * T_ + sg;
    const int lco = wave * 512;

    int koff[2][4];   // swizzled frag offsets (K: row=key; V: row=d)
    #pragma unroll
    for (int ks = 0; ks < 2; ++ks)
        #pragma unroll
        for (int n = 0; n < 4; ++n) {
            const int rr = n * 16 + col;
            koff[ks][n] = (rr >> 3) * 512 + (rr & 7) * 64 +
                          ((((ks << 2) | quad)) ^ (rr & 7)) * 8;
        }

    // shuffle sources for P C/D -> A-operand transform
    const int srcA = col + ((quad & 1) << 5);   // lane of q-group q' = 2*(quad&1)
    const int srcB = srcA + 16;                 // q' + 1
    const bool hi = (quad >> 1) != 0;           // use n = 2ks+1 ?

#define STAGE2(BUF, C0)                                                        \
    {                                                                          \
        const size_t jj = (size_t)(C0) * 64;                                   \
        GLD_LDS(kg + jj * D_, &Ks[BUF][lco]);                                  \
        GLD_LDS(vg + jj, &Vt[BUF][lco]);                                       \
        GLD_LDS(kg + (jj + 64) * D_, &Ks[BUF][4096 + lco]);                    \
        GLD_LDS(vg + jj + 64, &Vt[BUF][4096 + lco]);                           \
    }

#define CHUNK_COMPUTE(BUF, SUB, J0, DIAG)                                      \
    {                                                                          \
        const int j0_ = (J0);                                                  \
        const u16* ksb = &Ks[BUF][(SUB) * 4096];                               \
        const u16* vsb = &Vt[BUF][(SUB) * 4096];                               \
        /* S^T = K Q^T : A = K (m=key), B = Q (n=q) */                         \
        f32x4 s[4] = {};                                                       \
        __builtin_amdgcn_s_setprio(1);                                         \
        _Pragma("unroll")                                                      \
        for (int ks = 0; ks < 2; ++ks)                                         \
            _Pragma("unroll")                                                  \
            for (int n = 0; n < 4; ++n) {                                      \
                const bf16x8 kf = *(const bf16x8*)(ksb + koff[ks][n]);         \
                s[n] = __builtin_amdgcn_mfma_f32_16x16x32_bf16(                \
                    kf, qf[ks], s[n], 0, 0, 0);                                \
            }                                                                  \
        __builtin_amdgcn_s_setprio(0);                                         \
        /* P = exp2(S*scale*log2e), masked on diagonal chunk; pack f16 */      \
        u32 pk[4][2];                                                          \
        _Pragma("unroll")                                                      \
        for (int n = 0; n < 4; ++n) {                                          \
            float p[4];                                                        \
            _Pragma("unroll")                                                  \
            for (int r = 0; r < 4; ++r) {                                      \
                float pv = __builtin_amdgcn_exp2f(s[n][r] * 0.1803368801f);    \
                if (DIAG && (j0_ + n * 16 + quad * 4 + r > qrow)) pv = 0.0f;   \
                p[r] = pv;                                                     \
                lsv[r] += pv;                                                  \
            }                                                                  \
            union { fp16x2 h; u32 u; } c0u, c1u;                               \
            c0u.h = __builtin_amdgcn_cvt_pkrtz(p[0], p[1]);                    \
            c1u.h = __builtin_amdgcn_cvt_pkrtz(p[2], p[3]);                    \
            pk[n][0] = c0u.u;                                                  \
            pk[n][1] = c1u.u;                                                  \
        }                                                                      \
        /* O += P V : A-frag of P built by in-wave shuffles */                 \
        _Pragma("unroll")                                                      \
        for (int ks = 0; ks < 2; ++ks) {                                       \
            const int nl = 2 * ks, nh = nl + 1;                                \
            const u32 w0a = __shfl(pk[nl][0], srcA);                           \
            const u32 w0b = __shfl(pk[nh][0], srcA);                           \
            const u32 w1a = __shfl(pk[nl][1], srcA);                           \
            const u32 w1b = __shfl(pk[nh][1], srcA);                           \
            const u32 w2a = __shfl(pk[nl][0], srcB);                           \
            const u32 w2b = __shfl(pk[nh][0], srcB);                           \
            const u32 w3a = __shfl(pk[nl][1], srcB);                           \
            const u32 w3b = __shfl(pk[nh][1], srcB);                           \
            union { u32 u[4]; f16x8 v; } af;                                   \
            af.u[0] = hi ? w0b : w0a;                                          \
            af.u[1] = hi ? w1b : w1a;                                          \
            af.u[2] = hi ? w2b : w2a;                                          \
            af.u[3] = hi ? w3b : w3a;                                          \
            __builtin_amdgcn_s_setprio(1);                                     \
            _Pragma("unroll")                                                  \
            for (int n = 0; n < 4; ++n) {                                      \
                const f16x8 vf = *(const f16x8*)(vsb + koff[ks][n]);           \
                o[n] = __builtin_amdgcn_mfma_f32_16x16x32_f16(                 \
                    af.v, vf, o[n], 0, 0, 0);                                  \
            }                                                                  \
            __builtin_amdgcn_s_setprio(0);                                     \
        }                                                                      \
    }

    for (int half = 0; half < 2; ++half) {
        const int qt = half ? pr : (31 - pr);
        const int q0 = qt * 64;
        const int qrow = q0 + wq * 16 + col;
        const int nchunks = qt + 1;
        const int niter = (nchunks + 1) >> 1;

        // Q B-fragments: lane holds Q[q=col][d=ks*32+quad*8+j]
        const u16* qbase = qb + ((size_t)bh * T_ + q0 + wq * 16) * D_;
        bf16x8 qf[2];
        #pragma unroll
        for (int ks = 0; ks < 2; ++ks)
            qf[ks] = *(const bf16x8*)(qbase + col * D_ + ks * 32 + quad * 8);

        f32x4 o[4] = {};
        float lsv[4] = {};

        // guard LDS reuse across halves / combine scratch (full drain)
        __syncthreads();
        // prologue: sub-tiles {0,1} into buf 0 (4 loads in flight)
        STAGE2(0, 0)

        int buf = 0;
        for (int it = 0; it + 1 < niter; ++it) {
            // read-safety: all waves done reading the buffer we overwrite
            asm volatile("s_barrier" ::: "memory");
            STAGE2(buf ^ 1, 2 * (it + 1))   // +4 loads (8 outstanding)
            // wait for the OLDER 4 (buf's data); prefetch stays in flight
            asm volatile("s_waitcnt vmcnt(4)" ::: "memory");
            asm volatile("s_barrier" ::: "memory");
            // group's sub-chunk c = 2*it+grp <= nchunks-2 < qt: never diag
            CHUNK_COMPUTE(buf, grp, (2 * it + grp) * 64, false)
            buf ^= 1;
        }
        __syncthreads();   // full drain for the final iter's DMA
        {
            const int cf = 2 * (niter - 1) + grp;
            if (cf <= qt) {
                if (cf == qt) { CHUNK_COMPUTE(buf, grp, cf * 64, true) }
                else         { CHUNK_COMPUTE(buf, grp, cf * 64, false) }
            }
        }

        // combine group partials (linear: no-max softmax) via LDS scratch,
        // then group 0 reduces + writes. Scratch overlays Ks (dead now).
        __syncthreads();   // all K/V reads done before scratch overwrite
        float* scratch = (float*)&Ks[0][0];   // 4 waves*64 lanes*21 f32
        const int sidx = (wq * 64 + lane) * 21;
        if (grp == 1) {
            #pragma unroll
            for (int n = 0; n < 4; ++n)
                #pragma unroll
                for (int r = 0; r < 4; ++r)
                    scratch[sidx + n * 4 + r] = o[n][r];
            #pragma unroll
            for (int r = 0; r < 4; ++r)
                scratch[sidx + 16 + r] = lsv[r];
        }
        __syncthreads();
        if (grp == 0) {
            #pragma unroll
            for (int n = 0; n < 4; ++n)
                #pragma unroll
                for (int r = 0; r < 4; ++r)
                    o[n][r] += scratch[sidx + n * 4 + r];
            #pragma unroll
            for (int r = 0; r < 4; ++r)
                lsv[r] += scratch[sidx + 16 + r];

            float l = (lsv[0] + lsv[1]) + (lsv[2] + lsv[3]);
            l += __shfl_xor(l, 16);
            l += __shfl_xor(l, 32);
            const float inv = 1.0f / l;
            float invr[4];
            #pragma unroll
            for (int r = 0; r < 4; ++r)
                invr[r] = __shfl(inv, quad * 4 + r);   // inv for q = quad*4+r
            #pragma unroll
            for (int r = 0; r < 4; ++r) {
                const int row = q0 + wq * 16 + quad * 4 + r;
                u16* yp = y + (size_t)(b * T_ + row) * C_ + h * D_;
                #pragma unroll
                for (int n = 0; n < 4; ++n)
                    yp[n * 16 + col] = f2bf(o[n][r] * invr[r]);
            }
        }
    }
#undef CHUNK_COMPUTE
#undef STAGE2
}

// ---------------------------------------------------------------------------
// Launch — R13 configuration (session best): BN=64 + depth-1 counted-vmcnt
// ---------------------------------------------------------------------------
extern "C" void kernel_launch(void* const* d_in, const int* in_sizes, int n_in,
                              void* d_out, int out_size, void* d_ws, size_t ws_size,
                              hipStream_t stream) {
    const float* x      = (const float*)d_in[0];
    const float* w_qkv  = (const float*)d_in[1];
    const float* w_proj = (const float*)d_in[2];
    float* out = (float*)d_out;

    const int M = B_ * T_;                   // 4096
    u16* xb  = (u16*)d_ws;
    u16* wqb = xb + NX_;
    u16* wpb = wqb + NWQ_;
    u16* qb  = wpb + NWP_;
    u16* kb  = qb + NX_;
    u16* vt  = kb + NX_;     // f16 (b,h,d,t)
    u16* yb  = vt + NX_;     // bf16 (b,t,h,d)
    float* tab = (float*)(yb + NX_);   // RoPE table, 512 KB

    cast_all<<<8192 + 128, 256, 0, stream>>>(x, w_qkv, w_proj, xb, tab);

    // qkv^T = w_qkv @ x^T, fused RoPE + split into qb/kb (bf16), vt (f16)
    // BN=64 + counted-vmcnt DBUF (R13-verified): 1536 blocks, 48 KB, 3/CU
    gemm64<1, 1, 64><<<dim3(M / 64, 3 * C_ / 128), 256, 0, stream>>>(
        wqb, xb, nullptr, qb, kb, vt, tab, 3 * C_, M, C_);

    attn_mfma<<<512, 512, 0, stream>>>(qb, kb, vt, yb);

    // out = y @ w_proj^T -> fp32
    // BN=64 + counted-vmcnt DBUF (R13-verified): 512 blocks = 2/CU, 48 KB
    gemm64<0, 1, 64><<<dim3(C_ / 64, M / 128), 256, 0, stream>>>(
        yb, wpb, out, nullptr, nullptr, nullptr, nullptr, M, C_, C_);
}